// Round 1
// baseline (216.458 us; speedup 1.0000x reference)
//
#include <hip/hip_runtime.h>
#include <hip/hip_bf16.h>

#define B_ 128
#define S_ 196
#define E_ 768
#define M_ 768
#define KTOT (S_*E_)      // 150528
#define SUPER 64
#define NT 96             // m-columns per workgroup
#define KSPLIT 64

typedef __bf16 bf16x8 __attribute__((ext_vector_type(8)));
typedef __bf16 bf16x4 __attribute__((ext_vector_type(4)));
typedef float  f32x4  __attribute__((ext_vector_type(4)));

__device__ inline bf16x8 cvt8(const float* __restrict__ p) {
    float4 a = *(const float4*)p;
    float4 b = *(const float4*)(p + 4);
    bf16x8 r;
    r[0] = (__bf16)a.x; r[1] = (__bf16)a.y; r[2] = (__bf16)a.z; r[3] = (__bf16)a.w;
    r[4] = (__bf16)b.x; r[5] = (__bf16)b.y; r[6] = (__bf16)b.z; r[7] = (__bf16)b.w;
    return r;
}

// out[b,m] = 0.9*mlp_b[m] + 0.1*fk_b[m]
__global__ void init_out(const float* __restrict__ mlp_b,
                         const float* __restrict__ fk_b,
                         float* __restrict__ out) {
    int i = blockIdx.x * 256 + threadIdx.x;
    if (i < B_ * M_) {
        int m = i % M_;
        out[i] = 0.9f * mlp_b[m] + 0.1f * fk_b[m];
    }
}

// event_pair[b, 0:768]   = mean(sent_emb[b, s1:e1, :])
// event_pair[b, 768:1536]= mean(sent_emb[b, s2:e2, :])
__global__ void event_pool(const float* __restrict__ SE,
                           const int* __restrict__ BE, int be_stride,
                           float* __restrict__ EP) {
    int b = blockIdx.x;
    int s1 = BE[(b*4 + 0) * be_stride];
    int e1 = BE[(b*4 + 1) * be_stride];
    int s2 = BE[(b*4 + 2) * be_stride];
    int e2 = BE[(b*4 + 3) * be_stride];
    float inv1 = 1.0f / (float)(e1 - s1);
    float inv2 = 1.0f / (float)(e2 - s2);
    for (int c = threadIdx.x; c < E_; c += 256) {
        float sum1 = 0.f, sum2 = 0.f;
        for (int s = s1; s < e1; ++s) sum1 += SE[((size_t)b * S_ + s) * E_ + c];
        for (int s = s2; s < e2; ++s) sum2 += SE[((size_t)b * S_ + s) * E_ + c];
        EP[b * (2*E_) + c]       = sum1 * inv1;
        EP[b * (2*E_) + E_ + c]  = sum2 * inv2;
    }
}

// out[b,m] += 0.9 * dot(EP[b,:], mlp_w[m,:])   K=1536, one wave per 16x16 tile
__global__ __launch_bounds__(256) void mlp_gemm(const float* __restrict__ EP,
                                                const float* __restrict__ Wm,
                                                float* __restrict__ out) {
    const int wid   = (blockIdx.x * 256 + threadIdx.x) >> 6;  // 0..383
    const int lane  = threadIdx.x & 63;
    const int bt    = wid & 7;    // b-tile 0..7
    const int mt    = wid >> 3;   // m-tile 0..47
    const int row16 = lane & 15;
    const int kgrp  = lane >> 4;
    const float* Arow = EP + (size_t)(bt*16 + row16) * (2*E_);
    const float* Brow = Wm + (size_t)(mt*16 + row16) * (2*E_);
    f32x4 acc = {};
    for (int k0 = 0; k0 < 2*E_; k0 += 32) {
        bf16x8 af = cvt8(Arow + k0 + kgrp*8);
        bf16x8 bv = cvt8(Brow + k0 + kgrp*8);
        acc = __builtin_amdgcn_mfma_f32_16x16x32_bf16(af, bv, acc, 0, 0, 0);
    }
    const int m = mt*16 + row16;
#pragma unroll
    for (int r = 0; r < 4; ++r) {
        const int b = bt*16 + kgrp*4 + r;
        out[b * M_ + m] += 0.9f * acc[r];  // unique writer per element in this kernel
    }
}

// out[b,m] += 0.1 * dot(A[b,:], W[m,:])  over K=150528, split-K atomic accumulate.
// Workgroup: 8 waves, tile = 128b x 96m x K-slice. W staged f32->bf16 in LDS
// (XOR swizzle (row&7)<<4 vs 128B-stride bank conflict); A read direct from
// global (LLC-resident).
__global__ __launch_bounds__(512, 4) void fk_gemm(const float* __restrict__ A,
                                                  const float* __restrict__ W,
                                                  float* __restrict__ out) {
    __shared__ __align__(16) char Wlds[NT * 128];  // 96 rows x 64 bf16 (128B/row)

    const int mt = blockIdx.x;          // 0..7
    const int kz = blockIdx.y;          // 0..KSPLIT-1
    const int ss_total = KTOT / SUPER;  // 2352 supersteps of 64 k
    const int ss0 = (ss_total * kz) / KSPLIT;
    const int ss1 = (ss_total * (kz + 1)) / KSPLIT;

    const int tid   = threadIdx.x;
    const int wave  = tid >> 6;         // 0..7 = b-tile
    const int lane  = tid & 63;
    const int row16 = lane & 15;
    const int kgrp  = lane >> 4;

    // W staging: 96x64 f32 = 1536 float4, 512 threads x 3
    const float* wp[3];
    int wbyte[3];
#pragma unroll
    for (int i = 0; i < 3; ++i) {
        int fid = tid + i * 512;
        int r = fid >> 4, cq = fid & 15;
        wp[i]    = W + (size_t)(mt * NT + r) * KTOT + cq * 4;
        wbyte[i] = r * 128 + ((cq * 8) ^ ((r & 7) << 4));
    }

    const float* Arow = A + (size_t)(wave * 16 + row16) * KTOT;
    const int swz = (row16 & 7) << 4;   // (r&7) == (row16&7) since n*16 % 8 == 0

    f32x4 acc[6] = {};

    for (int ss = ss0; ss < ss1; ++ss) {
        const int k0 = ss * SUPER;
#pragma unroll
        for (int i = 0; i < 3; ++i) {
            float4 v = *(const float4*)(wp[i] + k0);
            bf16x4 h;
            h[0] = (__bf16)v.x; h[1] = (__bf16)v.y; h[2] = (__bf16)v.z; h[3] = (__bf16)v.w;
            *(bf16x4*)(Wlds + wbyte[i]) = h;
        }
        __syncthreads();
#pragma unroll
        for (int kk = 0; kk < 2; ++kk) {
            bf16x8 af = cvt8(Arow + k0 + kk * 32 + kgrp * 8);
            const int cb = ((kk * 64 + kgrp * 16) ^ swz);
#pragma unroll
            for (int n = 0; n < 6; ++n) {
                bf16x8 wf = *(const bf16x8*)(Wlds + (n * 16 + row16) * 128 + cb);
                acc[n] = __builtin_amdgcn_mfma_f32_16x16x32_bf16(af, wf, acc[n], 0, 0, 0);
            }
        }
        __syncthreads();
    }

    // D layout: col = lane&15 (m), row = (lane>>4)*4 + reg (b)   [m89/m91]
#pragma unroll
    for (int n = 0; n < 6; ++n) {
        const int m = mt * NT + n * 16 + row16;
#pragma unroll
        for (int r = 0; r < 4; ++r) {
            const int b = wave * 16 + kgrp * 4 + r;
            atomicAdd(out + (size_t)b * M_ + m, 0.1f * acc[n][r]);
        }
    }
}

extern "C" void kernel_launch(void* const* d_in, const int* in_sizes, int n_in,
                              void* d_out, int out_size, void* d_ws, size_t ws_size,
                              hipStream_t stream) {
    const float* se    = (const float*)d_in[0];
    const int*   be    = (const int*)  d_in[1];
    const float* mlp_w = (const float*)d_in[2];
    const float* mlp_b = (const float*)d_in[3];
    const float* fk_w  = (const float*)d_in[4];
    const float* fk_b  = (const float*)d_in[5];
    float* out = (float*)d_out;
    float* ep  = (float*)d_ws;  // event_pair [128][1536] f32 = 786 KB

    // if batch_e arrived as int64 (2 words/elem, little-endian), stride the reads
    const int be_stride = (in_sizes[1] == B_ * 4 * 2) ? 2 : 1;

    init_out<<<(B_ * M_ + 255) / 256, 256, 0, stream>>>(mlp_b, fk_b, out);
    event_pool<<<B_, 256, 0, stream>>>(se, be, be_stride, ep);
    mlp_gemm<<<(B_ / 16) * (M_ / 16) / 4, 256, 0, stream>>>(ep, mlp_w, out);
    fk_gemm<<<dim3(M_ / NT, KSPLIT), 512, 0, stream>>>(se, fk_w, out);
}

// Round 2
// 213.166 us; speedup vs baseline: 1.0154x; 1.0154x over previous
//
#include <hip/hip_runtime.h>
#include <hip/hip_bf16.h>

#define B_ 128
#define S_ 196
#define E_ 768
#define M_ 768
#define KTOT (S_*E_)      // 150528
#define SUPER 64
#define NT 96             // m-columns per workgroup
#define KSPLIT 96
#define ZC 4              // z-chunks in reduce kernel

typedef __bf16 bf16x8 __attribute__((ext_vector_type(8)));
typedef __bf16 bf16x4 __attribute__((ext_vector_type(4)));
typedef float  f32x4  __attribute__((ext_vector_type(4)));

__device__ inline bf16x8 cvt8(const float* __restrict__ p) {
    float4 a = *(const float4*)p;
    float4 b = *(const float4*)(p + 4);
    bf16x8 r;
    r[0] = (__bf16)a.x; r[1] = (__bf16)a.y; r[2] = (__bf16)a.z; r[3] = (__bf16)a.w;
    r[4] = (__bf16)b.x; r[5] = (__bf16)b.y; r[6] = (__bf16)b.z; r[7] = (__bf16)b.w;
    return r;
}

// out[b,m] = 0.9*mlp_b[m] + 0.1*fk_b[m]
__global__ void init_out(const float* __restrict__ mlp_b,
                         const float* __restrict__ fk_b,
                         float* __restrict__ out) {
    int i = blockIdx.x * 256 + threadIdx.x;
    if (i < B_ * M_) {
        int m = i % M_;
        out[i] = 0.9f * mlp_b[m] + 0.1f * fk_b[m];
    }
}

__global__ void event_pool(const float* __restrict__ SE,
                           const int* __restrict__ BE, int be_stride,
                           float* __restrict__ EP) {
    int b = blockIdx.x;
    int s1 = BE[(b*4 + 0) * be_stride];
    int e1 = BE[(b*4 + 1) * be_stride];
    int s2 = BE[(b*4 + 2) * be_stride];
    int e2 = BE[(b*4 + 3) * be_stride];
    float inv1 = 1.0f / (float)(e1 - s1);
    float inv2 = 1.0f / (float)(e2 - s2);
    for (int c = threadIdx.x; c < E_; c += 256) {
        float sum1 = 0.f, sum2 = 0.f;
        for (int s = s1; s < e1; ++s) sum1 += SE[((size_t)b * S_ + s) * E_ + c];
        for (int s = s2; s < e2; ++s) sum2 += SE[((size_t)b * S_ + s) * E_ + c];
        EP[b * (2*E_) + c]       = sum1 * inv1;
        EP[b * (2*E_) + E_ + c]  = sum2 * inv2;
    }
}

// out[b,m] += 0.9 * dot(EP[b,:], mlp_w[m,:])   K=1536, one wave per 16x16 tile
__global__ __launch_bounds__(256) void mlp_gemm(const float* __restrict__ EP,
                                                const float* __restrict__ Wm,
                                                float* __restrict__ out) {
    const int wid   = (blockIdx.x * 256 + threadIdx.x) >> 6;  // 0..383
    const int lane  = threadIdx.x & 63;
    const int bt    = wid & 7;    // b-tile 0..7
    const int mt    = wid >> 3;   // m-tile 0..47
    const int row16 = lane & 15;
    const int kgrp  = lane >> 4;
    const float* Arow = EP + (size_t)(bt*16 + row16) * (2*E_);
    const float* Brow = Wm + (size_t)(mt*16 + row16) * (2*E_);
    f32x4 acc = {};
    for (int k0 = 0; k0 < 2*E_; k0 += 32) {
        bf16x8 af = cvt8(Arow + k0 + kgrp*8);
        bf16x8 bv = cvt8(Brow + k0 + kgrp*8);
        acc = __builtin_amdgcn_mfma_f32_16x16x32_bf16(af, bv, acc, 0, 0, 0);
    }
    const int m = mt*16 + row16;
#pragma unroll
    for (int r = 0; r < 4; ++r) {
        const int b = bt*16 + kgrp*4 + r;
        out[b * M_ + m] += 0.9f * acc[r];  // unique writer per element in this kernel
    }
}

// partial[kz][b][m] = dot(A[b,kslice], W[m,kslice])  -- split-K partial, plain stores.
// Workgroup: 8 waves, tile = 128b x 96m. W staged f32->bf16 in double-buffered
// LDS (XOR swizzle (row&7)<<4), depth-1 register prefetch, ONE barrier/superstep.
__global__ __launch_bounds__(512) void fk_gemm(const float* __restrict__ A,
                                               const float* __restrict__ W,
                                               float* __restrict__ partial) {
    __shared__ __align__(16) char Wlds[2][NT * 128];  // 2 x (96 rows x 64 bf16)

    const int mt = blockIdx.x;          // 0..7
    const int kz = blockIdx.y;          // 0..KSPLIT-1
    const int ss_total = KTOT / SUPER;  // 2352 supersteps of 64 k
    const int ss0 = (ss_total * kz) / KSPLIT;
    const int ss1 = (ss_total * (kz + 1)) / KSPLIT;

    const int tid   = threadIdx.x;
    const int wave  = tid >> 6;         // 0..7 = b-tile
    const int lane  = tid & 63;
    const int row16 = lane & 15;
    const int kgrp  = lane >> 4;

    // W staging: 96x64 f32 = 1536 float4, 512 threads x 3
    const float* wp[3];
    int wbyte[3];
#pragma unroll
    for (int i = 0; i < 3; ++i) {
        int fid = tid + i * 512;
        int r = fid >> 4, cq = fid & 15;
        wp[i]    = W + (size_t)(mt * NT + r) * KTOT + cq * 4;
        wbyte[i] = r * 128 + ((cq * 8) ^ ((r & 7) << 4));
    }

    const float* Arow = A + (size_t)(wave * 16 + row16) * KTOT;
    const int swz = (row16 & 7) << 4;   // row n*16+row16: (row&7)==(row16&7)

    f32x4 acc[6] = {};
    float4 v[3];

    // prologue: stage ss0 into buf 0
#pragma unroll
    for (int i = 0; i < 3; ++i) v[i] = *(const float4*)(wp[i] + ss0 * SUPER);
#pragma unroll
    for (int i = 0; i < 3; ++i) {
        bf16x4 h;
        h[0] = (__bf16)v[i].x; h[1] = (__bf16)v[i].y;
        h[2] = (__bf16)v[i].z; h[3] = (__bf16)v[i].w;
        *(bf16x4*)(&Wlds[0][0] + wbyte[i]) = h;
    }
    __syncthreads();

    for (int ss = ss0; ss < ss1; ++ss) {
        const int buf = (ss - ss0) & 1;
        const int k0 = ss * SUPER;
        const bool more = (ss + 1 < ss1);

        // issue next superstep's W loads (prefetch into regs)
        if (more) {
#pragma unroll
            for (int i = 0; i < 3; ++i) v[i] = *(const float4*)(wp[i] + k0 + SUPER);
        }

        // A fragments for both halves up front (LLC-resident)
        bf16x8 af0 = cvt8(Arow + k0 + kgrp * 8);
        bf16x8 af1 = cvt8(Arow + k0 + 32 + kgrp * 8);

        const char* Wb = &Wlds[buf][0];
#pragma unroll
        for (int n = 0; n < 6; ++n) {
            bf16x8 wf = *(const bf16x8*)(Wb + (n * 16 + row16) * 128 + ((kgrp * 16) ^ swz));
            acc[n] = __builtin_amdgcn_mfma_f32_16x16x32_bf16(af0, wf, acc[n], 0, 0, 0);
        }
#pragma unroll
        for (int n = 0; n < 6; ++n) {
            bf16x8 wf = *(const bf16x8*)(Wb + (n * 16 + row16) * 128 + ((64 + kgrp * 16) ^ swz));
            acc[n] = __builtin_amdgcn_mfma_f32_16x16x32_bf16(af1, wf, acc[n], 0, 0, 0);
        }

        // convert + write next buffer (safe: nobody reads buf^1 until the barrier)
        if (more) {
#pragma unroll
            for (int i = 0; i < 3; ++i) {
                bf16x4 h;
                h[0] = (__bf16)v[i].x; h[1] = (__bf16)v[i].y;
                h[2] = (__bf16)v[i].z; h[3] = (__bf16)v[i].w;
                *(bf16x4*)(&Wlds[buf ^ 1][0] + wbyte[i]) = h;
            }
        }
        __syncthreads();
    }

    // D layout: col = lane&15 (m), row = (lane>>4)*4 + reg (b)   [m89/m91]
    float* pz = partial + (size_t)kz * (B_ * M_);
#pragma unroll
    for (int n = 0; n < 6; ++n) {
        const int m = mt * NT + n * 16 + row16;
#pragma unroll
        for (int r = 0; r < 4; ++r) {
            const int b = wave * 16 + kgrp * 4 + r;
            pz[(size_t)b * M_ + m] = acc[n][r];
        }
    }
}

// out[i] += 0.1 * sum_kz partial[kz][i], z split into ZC chunks via atomics
__global__ void reduce_k(const float* __restrict__ pp, float* __restrict__ out) {
    int t = blockIdx.x * 256 + threadIdx.x;
    int i = t % (B_ * M_);
    int zc = t / (B_ * M_);
    if (zc >= ZC) return;
    float s = 0.f;
#pragma unroll
    for (int z = zc * (KSPLIT / ZC); z < (zc + 1) * (KSPLIT / ZC); ++z)
        s += pp[(size_t)z * (B_ * M_) + i];
    atomicAdd(out + i, 0.1f * s);
}

extern "C" void kernel_launch(void* const* d_in, const int* in_sizes, int n_in,
                              void* d_out, int out_size, void* d_ws, size_t ws_size,
                              hipStream_t stream) {
    const float* se    = (const float*)d_in[0];
    const int*   be    = (const int*)  d_in[1];
    const float* mlp_w = (const float*)d_in[2];
    const float* mlp_b = (const float*)d_in[3];
    const float* fk_w  = (const float*)d_in[4];
    const float* fk_b  = (const float*)d_in[5];
    float* out = (float*)d_out;
    float* ep  = (float*)d_ws;                  // event_pair [128][1536] f32
    float* pp  = ep + (size_t)B_ * 2 * E_;      // partials [KSPLIT][128][768] f32

    const int be_stride = (in_sizes[1] == B_ * 4 * 2) ? 2 : 1;

    init_out<<<(B_ * M_ + 255) / 256, 256, 0, stream>>>(mlp_b, fk_b, out);
    event_pool<<<B_, 256, 0, stream>>>(se, be, be_stride, ep);
    mlp_gemm<<<(B_ / 16) * (M_ / 16) / 4, 256, 0, stream>>>(ep, mlp_w, out);
    fk_gemm<<<dim3(M_ / NT, KSPLIT), 512, 0, stream>>>(se, fk_w, pp);
    reduce_k<<<(B_ * M_ * ZC + 255) / 256, 256, 0, stream>>>(pp, out);
}

// Round 3
// 190.197 us; speedup vs baseline: 1.1381x; 1.1208x over previous
//
#include <hip/hip_runtime.h>
#include <hip/hip_bf16.h>

#define B_ 128
#define S_ 196
#define E_ 768
#define M_ 768
#define KTOT (S_*E_)      // 150528
#define SUPER 64
#define NT 96             // m-columns per workgroup
#define KSPLIT 96
#define ZC 4              // z-chunks in reduce kernel

typedef __bf16 bf16x8 __attribute__((ext_vector_type(8)));
typedef __bf16 bf16x4 __attribute__((ext_vector_type(4)));
typedef float  f32x4  __attribute__((ext_vector_type(4)));

__device__ inline bf16x8 cvt8(const float* __restrict__ p) {
    float4 a = *(const float4*)p;
    float4 b = *(const float4*)(p + 4);
    bf16x8 r;
    r[0] = (__bf16)a.x; r[1] = (__bf16)a.y; r[2] = (__bf16)a.z; r[3] = (__bf16)a.w;
    r[4] = (__bf16)b.x; r[5] = (__bf16)b.y; r[6] = (__bf16)b.z; r[7] = (__bf16)b.w;
    return r;
}

// out[b,m] = 0.9*mlp_b[m] + 0.1*fk_b[m]
__global__ void init_out(const float* __restrict__ mlp_b,
                         const float* __restrict__ fk_b,
                         float* __restrict__ out) {
    int i = blockIdx.x * 256 + threadIdx.x;
    if (i < B_ * M_) {
        int m = i % M_;
        out[i] = 0.9f * mlp_b[m] + 0.1f * fk_b[m];
    }
}

// A (sent_emb) f32 -> bf16, row-major copy. 16B/lane stores.
__global__ void cvt_a(const float* __restrict__ A, __bf16* __restrict__ Abf) {
    const int n8 = (B_ * KTOT) / 8;  // 2408448 groups of 8
    for (int i = blockIdx.x * blockDim.x + threadIdx.x; i < n8;
         i += gridDim.x * blockDim.x) {
        *(bf16x8*)(Abf + (size_t)i * 8) = cvt8(A + (size_t)i * 8);
    }
}

__global__ void event_pool(const float* __restrict__ SE,
                           const int* __restrict__ BE, int be_stride,
                           float* __restrict__ EP) {
    int b = blockIdx.x;
    int s1 = BE[(b*4 + 0) * be_stride];
    int e1 = BE[(b*4 + 1) * be_stride];
    int s2 = BE[(b*4 + 2) * be_stride];
    int e2 = BE[(b*4 + 3) * be_stride];
    float inv1 = 1.0f / (float)(e1 - s1);
    float inv2 = 1.0f / (float)(e2 - s2);
    for (int c = threadIdx.x; c < E_; c += 256) {
        float sum1 = 0.f, sum2 = 0.f;
        for (int s = s1; s < e1; ++s) sum1 += SE[((size_t)b * S_ + s) * E_ + c];
        for (int s = s2; s < e2; ++s) sum2 += SE[((size_t)b * S_ + s) * E_ + c];
        EP[b * (2*E_) + c]       = sum1 * inv1;
        EP[b * (2*E_) + E_ + c]  = sum2 * inv2;
    }
}

// out[b,m] += 0.9 * dot(EP[b,:], mlp_w[m,:])   K=1536, one wave per 16x16 tile
__global__ __launch_bounds__(256) void mlp_gemm(const float* __restrict__ EP,
                                                const float* __restrict__ Wm,
                                                float* __restrict__ out) {
    const int wid   = (blockIdx.x * 256 + threadIdx.x) >> 6;  // 0..383
    const int lane  = threadIdx.x & 63;
    const int bt    = wid & 7;    // b-tile 0..7
    const int mt    = wid >> 3;   // m-tile 0..47
    const int row16 = lane & 15;
    const int kgrp  = lane >> 4;
    const float* Arow = EP + (size_t)(bt*16 + row16) * (2*E_);
    const float* Brow = Wm + (size_t)(mt*16 + row16) * (2*E_);
    f32x4 acc = {};
    for (int k0 = 0; k0 < 2*E_; k0 += 32) {
        bf16x8 af = cvt8(Arow + k0 + kgrp*8);
        bf16x8 bv = cvt8(Brow + k0 + kgrp*8);
        acc = __builtin_amdgcn_mfma_f32_16x16x32_bf16(af, bv, acc, 0, 0, 0);
    }
    const int m = mt*16 + row16;
#pragma unroll
    for (int r = 0; r < 4; ++r) {
        const int b = bt*16 + kgrp*4 + r;
        out[b * M_ + m] += 0.9f * acc[r];  // unique writer per element in this kernel
    }
}

// partial[kz][b][m] = dot(Abf[b,kslice], W[m,kslice])  -- split-K, plain stores.
// 8 waves, tile = 128b x 96m. W staged f32->bf16 in double-buffered LDS
// (XOR swizzle (row&7)<<4), depth-1 register prefetch, one barrier/superstep.
// A pre-converted bf16, read direct from global (L2-shared within kz group).
// XCD-pinning: flat wgid decoded so all 8 mt-wgs of a kz group land on the
// same XCD (assumes wg i -> XCD i%8 round-robin) and are dispatch-adjacent.
__global__ __launch_bounds__(512) void fk_gemm(const __bf16* __restrict__ Abf,
                                               const float* __restrict__ W,
                                               float* __restrict__ partial) {
    __shared__ __align__(16) char Wlds[2][NT * 128];  // 2 x (96 rows x 64 bf16)

    const int wgid = blockIdx.x;        // 0..767
    const int xcd  = wgid & 7;
    const int slot = wgid >> 3;         // 0..95 per-XCD sequence
    const int kz   = xcd + 8 * (slot >> 3);  // 0..95, 12 groups per XCD
    const int mt   = slot & 7;          // 0..7

    const int ss_total = KTOT / SUPER;  // 2352 supersteps of 64 k
    const int ss0 = (ss_total * kz) / KSPLIT;
    const int ss1 = (ss_total * (kz + 1)) / KSPLIT;

    const int tid   = threadIdx.x;
    const int wave  = tid >> 6;         // 0..7 = b-tile
    const int lane  = tid & 63;
    const int row16 = lane & 15;
    const int kgrp  = lane >> 4;

    // W staging: 96x64 f32 = 1536 float4, 512 threads x 3
    const float* wp[3];
    int wbyte[3];
#pragma unroll
    for (int i = 0; i < 3; ++i) {
        int fid = tid + i * 512;
        int r = fid >> 4, cq = fid & 15;
        wp[i]    = W + (size_t)(mt * NT + r) * KTOT + cq * 4;
        wbyte[i] = r * 128 + ((cq * 8) ^ ((r & 7) << 4));
    }

    const __bf16* Arow = Abf + (size_t)(wave * 16 + row16) * KTOT;
    const int swz = (row16 & 7) << 4;   // row n*16+row16: (row&7)==(row16&7)

    f32x4 acc[6] = {};
    float4 v[3];

    // prologue: stage ss0 into buf 0
#pragma unroll
    for (int i = 0; i < 3; ++i) v[i] = *(const float4*)(wp[i] + ss0 * SUPER);
#pragma unroll
    for (int i = 0; i < 3; ++i) {
        bf16x4 h;
        h[0] = (__bf16)v[i].x; h[1] = (__bf16)v[i].y;
        h[2] = (__bf16)v[i].z; h[3] = (__bf16)v[i].w;
        *(bf16x4*)(&Wlds[0][0] + wbyte[i]) = h;
    }
    __syncthreads();

    for (int ss = ss0; ss < ss1; ++ss) {
        const int buf = (ss - ss0) & 1;
        const int k0 = ss * SUPER;
        const bool more = (ss + 1 < ss1);

        // issue next superstep's W loads (prefetch into regs)
        if (more) {
#pragma unroll
            for (int i = 0; i < 3; ++i) v[i] = *(const float4*)(wp[i] + k0 + SUPER);
        }

        // A fragments, bf16 direct (L2-resident within kz group)
        bf16x8 af0 = *(const bf16x8*)(Arow + k0 + kgrp * 8);
        bf16x8 af1 = *(const bf16x8*)(Arow + k0 + 32 + kgrp * 8);

        const char* Wb = &Wlds[buf][0];
#pragma unroll
        for (int n = 0; n < 6; ++n) {
            bf16x8 wf = *(const bf16x8*)(Wb + (n * 16 + row16) * 128 + ((kgrp * 16) ^ swz));
            acc[n] = __builtin_amdgcn_mfma_f32_16x16x32_bf16(af0, wf, acc[n], 0, 0, 0);
        }
#pragma unroll
        for (int n = 0; n < 6; ++n) {
            bf16x8 wf = *(const bf16x8*)(Wb + (n * 16 + row16) * 128 + ((64 + kgrp * 16) ^ swz));
            acc[n] = __builtin_amdgcn_mfma_f32_16x16x32_bf16(af1, wf, acc[n], 0, 0, 0);
        }

        // convert + write next buffer (safe: nobody reads buf^1 until the barrier)
        if (more) {
#pragma unroll
            for (int i = 0; i < 3; ++i) {
                bf16x4 h;
                h[0] = (__bf16)v[i].x; h[1] = (__bf16)v[i].y;
                h[2] = (__bf16)v[i].z; h[3] = (__bf16)v[i].w;
                *(bf16x4*)(&Wlds[buf ^ 1][0] + wbyte[i]) = h;
            }
        }
        __syncthreads();
    }

    // D layout: col = lane&15 (m), row = (lane>>4)*4 + reg (b)   [m89/m91]
    float* pz = partial + (size_t)kz * (B_ * M_);
#pragma unroll
    for (int n = 0; n < 6; ++n) {
        const int m = mt * NT + n * 16 + row16;
#pragma unroll
        for (int r = 0; r < 4; ++r) {
            const int b = wave * 16 + kgrp * 4 + r;
            pz[(size_t)b * M_ + m] = acc[n][r];
        }
    }
}

// out[i] += 0.1 * sum_kz partial[kz][i], z split into ZC chunks via atomics
__global__ void reduce_k(const float* __restrict__ pp, float* __restrict__ out) {
    int t = blockIdx.x * 256 + threadIdx.x;
    int i = t % (B_ * M_);
    int zc = t / (B_ * M_);
    if (zc >= ZC) return;
    float s = 0.f;
#pragma unroll
    for (int z = zc * (KSPLIT / ZC); z < (zc + 1) * (KSPLIT / ZC); ++z)
        s += pp[(size_t)z * (B_ * M_) + i];
    atomicAdd(out + i, 0.1f * s);
}

extern "C" void kernel_launch(void* const* d_in, const int* in_sizes, int n_in,
                              void* d_out, int out_size, void* d_ws, size_t ws_size,
                              hipStream_t stream) {
    const float* se    = (const float*)d_in[0];
    const int*   be    = (const int*)  d_in[1];
    const float* mlp_w = (const float*)d_in[2];
    const float* mlp_b = (const float*)d_in[3];
    const float* fk_w  = (const float*)d_in[4];
    const float* fk_b  = (const float*)d_in[5];
    float* out = (float*)d_out;
    float* ep  = (float*)d_ws;                  // event_pair [128][1536] f32
    float* pp  = ep + (size_t)B_ * 2 * E_;      // partials [KSPLIT][128][768] f32
    __bf16* abf = (__bf16*)(pp + (size_t)KSPLIT * B_ * M_);  // A bf16 [128][150528]

    const int be_stride = (in_sizes[1] == B_ * 4 * 2) ? 2 : 1;

    init_out<<<(B_ * M_ + 255) / 256, 256, 0, stream>>>(mlp_b, fk_b, out);
    cvt_a<<<2048, 256, 0, stream>>>(se, abf);
    event_pool<<<B_, 256, 0, stream>>>(se, be, be_stride, ep);
    mlp_gemm<<<(B_ / 16) * (M_ / 16) / 4, 256, 0, stream>>>(ep, mlp_w, out);
    fk_gemm<<<8 * KSPLIT, 512, 0, stream>>>(abf, fk_w, pp);
    reduce_k<<<(B_ * M_ * ZC + 255) / 256, 256, 0, stream>>>(pp, out);
}